// Round 9
// baseline (176.975 us; speedup 1.0000x reference)
//
#include <hip/hip_runtime.h>

#define NTOK 32
#define PADT 1
#define MLEN 512
#define NLEN 1024
#define EPS_F 1e-7f

#define CCH 128
#define NC  8
#define NWAVE 2
#define NPHASE (NC + NWAVE - 1)   // 9

// LDS float offsets. tok+wtmp+bnd sit BEFORE nl as front guard for negative
// stream underflow (down to -63); tail pad covers prefetch overrun (+128).
#define OFF_TOK 0                          // tok[512] int
#define OFF_WT  512                        // wtmp[16]
#define OFF_BND 528                        // bnd[2][272]: boundary ring, data at [64..192)
#define OFF_NL  1072                       // nl[32][1024] fp32
#define LDS_FLOATS (OFF_NL + NTOK*NLEN + 128)   // 33968 floats = 135,872 B

__device__ __forceinline__ float min3f(float a, float b, float c) {
  return fminf(fminf(a, b), c);   // folds to v_min3_f32
}
// result[lane l] = src[l-1] for l>=1; old[l] for lane 0
__device__ __forceinline__ float dpp_shr1(float old_v, float src) {
  return __int_as_float(__builtin_amdgcn_update_dpp(
      __float_as_int(old_v), __float_as_int(src), 0x138, 0xF, 0xF, false));
}

// One iteration = 4 column-slots. Lane l owns rows R+1..R+4 (R = 256*wv+4*lane);
// at slot s it computes col j = c*128 + (s-l) + 1 for its 4 rows.
// z[r] = V[R+1+r][j-1] entering the slot; ztop = V[R][j-1]; up = V[R][j] comes
// from lane-1's z[3] via DPP (lane 0: row-0 running prefix for wave 0, or the
// boundary ring written by wave 0 for wave 1). Loads issued here -> next call.
template <bool MASKED, bool WZERO>
__device__ __forceinline__ void dp_iter4(
    const float* (&P)[5], const float*& pb,
    float (&C)[6][4], float (&N)[6][4],
    float& ztop, float (&z)[4], float& run,
    int& s, const int lane, float* __restrict__ bw)
{
  // prefetch next 4 slots of all streams
#pragma unroll
  for (int r = 0; r < 5; ++r) {
#pragma unroll
    for (int c = 0; c < 4; ++c) N[r][c] = P[r][4 + c];
    P[r] += 4;
  }
  if (!WZERO) {
#pragma unroll
    for (int c = 0; c < 4; ++c) N[5][c] = pb[4 + c];
    pb += 4;
  }
#pragma unroll
  for (int j = 0; j < 4; ++j) {
    float insv = C[4][j];
    float runn = run + insv;                       // wave0 lane0: D[0][j]
    float upin = WZERO ? runn : C[5][j];
    float up = dpp_shr1(upin, z[3]);               // V[R][j]
    float nm0 = min3f(ztop + C[0][j], z[0] + insv, up  + 1.0f);
    float nm1 = min3f(z[0] + C[1][j], z[1] + insv, nm0 + 1.0f);
    float nm2 = min3f(z[1] + C[2][j], z[2] + insv, nm1 + 1.0f);
    float nm3 = min3f(z[2] + C[3][j], z[3] + insv, nm2 + 1.0f);
    bool act = true;
    if (MASKED) {
      act = ((unsigned)(s + j - lane)) < 128u;
      ztop = act ? up : ztop;
      z[0] = act ? nm0 : z[0];  z[1] = act ? nm1 : z[1];
      z[2] = act ? nm2 : z[2];  z[3] = act ? nm3 : z[3];
      if (WZERO) run = act ? runn : run;
    } else {
      ztop = up; z[0] = nm0; z[1] = nm1; z[2] = nm2; z[3] = nm3;
      if (WZERO) run = runn;
    }
    if (WZERO) {                                   // export bottom row V[256][j]
      if (lane == 63 && (!MASKED || act)) bw[s + j - 63] = nm3;
    }
  }
  s += 4;
}

template <bool MASKED, bool WZERO>
__device__ __forceinline__ void dp_iter8(
    const float* (&P)[5], const float*& pb,
    float (&C)[6][4], float (&N)[6][4],
    float& ztop, float (&z)[4], float& run,
    int& s, const int lane, float* __restrict__ bw)
{
  dp_iter4<MASKED, WZERO>(P, pb, C, N, ztop, z, run, s, lane, bw);
  dp_iter4<MASKED, WZERO>(P, pb, N, C, ztop, z, run, s, lane, bw);
}

__global__ __launch_bounds__(128, 1) void align_loss_kernel(
    const int* __restrict__ y_true, const float* __restrict__ y_pred,
    float* __restrict__ partial)
{
  extern __shared__ float smem[];
  int*   tok  = (int*)(smem + OFF_TOK);
  float* wtmp = smem + OFF_WT;
  int*   wti  = (int*)wtmp;
  float* bnd  = smem + OFF_BND;
  float* nl   = smem + OFF_NL;

  const int b = blockIdx.x;
  const int t = threadIdx.x;
  const int lane = t & 63;
  const int wv = t >> 6;           // 0 or 1

  // ---- zero token buffer ----
  tok[t] = 0; tok[t + 128] = 0; tok[t + 256] = 0; tok[t + 384] = 0;
  __syncthreads();

  // ---- Phase A: left-shift compaction (4 chunks of 128, order-preserving) ----
  int total = 0;
  for (int h = 0; h < 4; ++h) {
    int yt = y_true[b * MLEN + h * 128 + t];
    bool f = (yt != PADT);
    unsigned long long m = __ballot(f);
    int wp = __popcll(m & ((1ull << lane) - 1ull));
    if (lane == 0) wti[wv] = __popcll(m);
    __syncthreads();
    int offs = total + (wv ? wti[0] : 0) + wp;
    if (f) tok[offs] = yt;
    total += wti[0] + wti[1];
    __syncthreads();
  }
  const int L = total;

  // ---- Phase B: nl[tk][r] = -log(clip(y_pred[b,r,tk]/sum)), fp32 ----
  for (int r = t; r < NLEN; r += 128) {
    const float4* rp = (const float4*)(y_pred + ((size_t)b * NLEN + r) * NTOK);
    float4 q[8]; float sm = 0.f;
#pragma unroll
    for (int u = 0; u < 8; ++u) { q[u] = rp[u]; sm += q[u].x + q[u].y + q[u].z + q[u].w; }
    float inv = 1.0f / sm;
#pragma unroll
    for (int u = 0; u < 8; ++u) {
      float pv[4] = {q[u].x, q[u].y, q[u].z, q[u].w};
#pragma unroll
      for (int c2 = 0; c2 < 4; ++c2) {
        float p = pv[c2] * inv;
        p = fminf(fmaxf(p, EPS_F), 1.0f - EPS_F);
        nl[(u * 4 + c2) * NLEN + r] = -__logf(p);
      }
    }
  }
  __syncthreads();

  // ---- persistent DP state: lane owns rows R+1..R+4, R = 256*wv + 4*lane ----
  const int R = 256 * wv + 4 * lane;
  int tk0 = tok[R + 0], tk1 = tok[R + 1], tk2 = tok[R + 2], tk3 = tok[R + 3];
  float z[4];
#pragma unroll
  for (int r = 0; r < 4; ++r) z[r] = (float)(R + 1 + r);   // D[i][0] = i
  float ztop = (float)R;
  float run = 0.0f;                                         // row-0 prefix (wave 0)

  // ---- systolic phases: wave wv processes chunk c = p - wv ----
  for (int p = 0; p < NPHASE; ++p) {
    __syncthreads();
    const int c = p - wv;
    if (c < 0 || c >= NC) continue;
    const int base = c * CCH;

    const float* P[5];
    P[0] = nl + tk0 * NLEN + base - lane;
    P[1] = nl + tk1 * NLEN + base - lane;
    P[2] = nl + tk2 * NLEN + base - lane;
    P[3] = nl + tk3 * NLEN + base - lane;
    P[4] = nl + PADT * NLEN + base - lane;          // ins stream
    const float* pb = bnd + (c & 1) * 272 + 64 - lane;   // inject ring (wave 1)
    float* bw = bnd + (c & 1) * 272 + 64;                // export ring (wave 0)

    float C[6][4], N[6][4];
#pragma unroll
    for (int r = 0; r < 5; ++r) {
#pragma unroll
      for (int c2 = 0; c2 < 4; ++c2) C[r][c2] = P[r][c2];
    }
    if (wv == 1) {
#pragma unroll
      for (int c2 = 0; c2 < 4; ++c2) C[5][c2] = pb[c2];
    }

    int s = 0;
    if (wv == 0) {
      for (int it = 0; it < 8; ++it) dp_iter8<true,  true>(P, pb, C, N, ztop, z, run, s, lane, bw);
      for (int it = 0; it < 8; ++it) dp_iter8<false, true>(P, pb, C, N, ztop, z, run, s, lane, bw);
      for (int it = 0; it < 8; ++it) dp_iter8<true,  true>(P, pb, C, N, ztop, z, run, s, lane, bw);
    } else {
      for (int it = 0; it < 8; ++it) dp_iter8<true,  false>(P, pb, C, N, ztop, z, run, s, lane, bw);
      for (int it = 0; it < 8; ++it) dp_iter8<false, false>(P, pb, C, N, ztop, z, run, s, lane, bw);
      for (int it = 0; it < 8; ++it) dp_iter8<true,  false>(P, pb, C, N, ztop, z, run, s, lane, bw);
    }
  }

  // ---- extract D[L][1024] from frozen registers ----
  if (L == 0) {
    if (wv == 0 && lane == 63) partial[b] = run;    // D[0][1024] = full ins prefix
  } else {
    const int w_own = (L - 1) >> 8;
    const int li = ((L - 1) >> 2) & 63;
    const int ri = (L - 1) & 3;
    if (wv == w_own && lane == li) {
      float s01 = (ri & 1) ? z[1] : z[0];
      float s23 = (ri & 1) ? z[3] : z[2];
      partial[b] = (ri & 2) ? s23 : s01;
    }
  }
}

__global__ void reduce_kernel(const float* __restrict__ partial, float* __restrict__ out) {
  if (threadIdx.x == 0) {
    float s = 0.f;
    for (int b2 = 0; b2 < 32; ++b2) s += partial[b2];
    out[0] = s;
  }
}

extern "C" void kernel_launch(void* const* d_in, const int* in_sizes, int n_in,
                              void* d_out, int out_size, void* d_ws, size_t ws_size,
                              hipStream_t stream) {
  const int*   y_true = (const int*)d_in[0];
  const float* y_pred = (const float*)d_in[1];
  float* out = (float*)d_out;
  float* partial = (float*)d_ws;

  const size_t lds_bytes = (size_t)LDS_FLOATS * sizeof(float);   // 135,872 B
  hipFuncSetAttribute((const void*)align_loss_kernel,
                      hipFuncAttributeMaxDynamicSharedMemorySize, (int)lds_bytes);

  hipLaunchKernelGGL(align_loss_kernel, dim3(32), dim3(128), lds_bytes, stream,
                     y_true, y_pred, partial);
  hipLaunchKernelGGL(reduce_kernel, dim3(1), dim3(64), 0, stream, partial, out);
}

// Round 10
// 97.017 us; speedup vs baseline: 1.8242x; 1.8242x over previous
//
#include <hip/hip_runtime.h>

#define NTOK 32
#define PADT 1
#define MLEN 512
#define NLEN 1024
#define EPS_F 1e-7f
#define CCH  128
#define NC   8
#define NWAVE 4
#define NPHASE (NC + NWAVE - 1)   // 11
#define RSTR 224                  // ring stride (floats); >= 200 for prefetch overrun

// LDS float offsets
#define OFF_P0   0                      // P0s[1280] fp32 row-0 prefix (+pad for overread)
#define OFF_BND  1280                   // 7 rings x 224 (ifaces 0..2 x 2 parity + dead)
#define OFF_TOK  2848                   // tok[512] int
#define OFF_WT   3360                   // wtmp[16]
#define OFF_NLA  3376                   // bf16 A[32][1024] = 16384 float-words
#define OFF_NLB  19760                  // bf16 B[32][1024], B_u16[x] = A_u16[x+1]
#define LDS_FLOATS (OFF_NLB + 16384 + 160)   // 36304 floats = 145,216 B

typedef float f32x4 __attribute__((ext_vector_type(4)));

__device__ __forceinline__ float min3f(float a, float b, float c) {
  return fminf(fminf(a, b), c);
}
__device__ __forceinline__ float dpp_shr1(float old_v, float src) {
  return __int_as_float(__builtin_amdgcn_update_dpp(
      __float_as_int(old_v), __float_as_int(src), 0x138, 0xF, 0xF, false));
}
__device__ __forceinline__ ushort f2bf(float x) {   // RNE, x positive finite
  unsigned u = __float_as_uint(x);
  unsigned r = u + 0x7FFFu + ((u >> 16) & 1u);
  return (ushort)(r >> 16);
}
__device__ __forceinline__ unsigned lds_off(const void* p) {
  return (unsigned)(uintptr_t)p;     // low 32 bits of shared-aperture addr = LDS byte offset
}

// Issue the 14 loads for the NEXT iteration (12 x b32 pair-streams, 2 x b128 boundary).
// Volatile asm: order among asms is fixed; compiler cannot sink/merge them.
#define ISSUE_LOADS(U0, U1, UI, BV) \
  asm volatile("ds_read_b32 %0, %1"            : "=v"(U0[0]) : "v"(a0)); \
  asm volatile("ds_read_b32 %0, %1 offset:4"   : "=v"(U0[1]) : "v"(a0)); \
  asm volatile("ds_read_b32 %0, %1 offset:8"   : "=v"(U0[2]) : "v"(a0)); \
  asm volatile("ds_read_b32 %0, %1 offset:12"  : "=v"(U0[3]) : "v"(a0)); \
  asm volatile("ds_read_b32 %0, %1"            : "=v"(U1[0]) : "v"(a1)); \
  asm volatile("ds_read_b32 %0, %1 offset:4"   : "=v"(U1[1]) : "v"(a1)); \
  asm volatile("ds_read_b32 %0, %1 offset:8"   : "=v"(U1[2]) : "v"(a1)); \
  asm volatile("ds_read_b32 %0, %1 offset:12"  : "=v"(U1[3]) : "v"(a1)); \
  asm volatile("ds_read_b32 %0, %1"            : "=v"(UI[0]) : "v"(ai)); \
  asm volatile("ds_read_b32 %0, %1 offset:4"   : "=v"(UI[1]) : "v"(ai)); \
  asm volatile("ds_read_b32 %0, %1 offset:8"   : "=v"(UI[2]) : "v"(ai)); \
  asm volatile("ds_read_b32 %0, %1 offset:12"  : "=v"(UI[3]) : "v"(ai)); \
  asm volatile("ds_read_b128 %0, %1"           : "=v"(BV[0]) : "v"(ab)); \
  asm volatile("ds_read_b128 %0, %1 offset:16" : "=v"(BV[1]) : "v"(ab)); \
  a0 += 16; a1 += 16; ai += 16; ab += 32;

// Wait for the PREVIOUS iteration's 14 loads (exactly 14 newer asm loads are
// outstanding), fence the scheduler, then compute 8 slots from prev-iter regs.
#define COMPUTE(M, U0, U1, UI, BV) { \
  asm volatile("s_waitcnt lgkmcnt(14)"); \
  __builtin_amdgcn_sched_barrier(0); \
  float C0[8], C1[8], CI[8], CB[8]; \
  _Pragma("unroll") \
  for (int m2 = 0; m2 < 4; ++m2) { \
    C0[2*m2] = __uint_as_float(U0[m2] << 16); C0[2*m2+1] = __uint_as_float(U0[m2] & 0xFFFF0000u); \
    C1[2*m2] = __uint_as_float(U1[m2] << 16); C1[2*m2+1] = __uint_as_float(U1[m2] & 0xFFFF0000u); \
    CI[2*m2] = __uint_as_float(UI[m2] << 16); CI[2*m2+1] = __uint_as_float(UI[m2] & 0xFFFF0000u); \
  } \
  CB[0]=BV[0].x; CB[1]=BV[0].y; CB[2]=BV[0].z; CB[3]=BV[0].w; \
  CB[4]=BV[1].x; CB[5]=BV[1].y; CB[6]=BV[1].z; CB[7]=BV[1].w; \
  _Pragma("unroll") \
  for (int k = 0; k < 8; ++k) { \
    float up0 = dpp_shr1(CB[k], dcur1); \
    float m0 = min3f(diag0 + C0[k], up0 + 1.0f, dcur0 + CI[k]); \
    float m1 = min3f(dcur0 + C1[k], m0 + 1.0f, dcur1 + CI[k]); \
    if (M) { \
      int rsk = sb + k - lane; \
      bool act = ((unsigned)rsk) < 128u; \
      diag0 = (rsk < 128) ? up0 : diag0; \
      dcur0 = act ? m0 : dcur0; \
      dcur1 = act ? m1 : dcur1; \
    } else { \
      diag0 = up0; dcur0 = m0; dcur1 = m1; \
    } \
    switch ((k + 1) & 3) { \
      case 0: wq0 = m1; break; case 1: wq1 = m1; break; \
      case 2: wq2 = m1; break; case 3: wq3 = m1; break; } \
    if (k == 2 || k == 6) { \
      int q63 = sb + k - 63; \
      if (lane == 63 && q63 >= 3 && q63 < 128) \
        *(float4*)(bw + (q63 - 3)) = make_float4(wq0, wq1, wq2, wq3); \
    } \
  } \
  sb += 8; }

#define STEP_AB(M) { ISSUE_LOADS(u0b, u1b, uib, bb4) COMPUTE(M, u0a, u1a, uia, ba4) }
#define STEP_BA(M) { ISSUE_LOADS(u0a, u1a, uia, ba4) COMPUTE(M, u0b, u1b, uib, bb4) }

__global__ __launch_bounds__(256, 1) void align_loss_kernel(
    const int* __restrict__ y_true, const float* __restrict__ y_pred,
    float* __restrict__ partial)
{
  extern __shared__ float smem[];
  float* P0s  = smem + OFF_P0;
  float* bnd  = smem + OFF_BND;
  int*   tok  = (int*)(smem + OFF_TOK);
  float* wtmp = smem + OFF_WT;
  int*   wti  = (int*)wtmp;
  ushort* nlA = (ushort*)(smem + OFF_NLA);
  ushort* nlB = (ushort*)(smem + OFF_NLB);

  const int b = blockIdx.x;
  const int t = threadIdx.x;
  const int lane = t & 63;
  const int wv = t >> 6;

  // ---- zero token buffer ----
  tok[t] = 0; tok[t + 256] = 0;
  __syncthreads();

  // ---- Phase A: left-shift compaction (2 halves of 256) ----
  int total = 0;
  for (int h = 0; h < 2; ++h) {
    int yt = y_true[b * MLEN + h * 256 + t];
    bool f = (yt != PADT);
    unsigned long long m = __ballot(f);
    int wp = __popcll(m & ((1ull << lane) - 1ull));
    if (lane == 0) wti[8 + wv] = __popcll(m);
    __syncthreads();
    int offs = total, ht = 0;
#pragma unroll
    for (int w2 = 0; w2 < NWAVE; ++w2) { int cnt = wti[8 + w2]; if (w2 < wv) offs += cnt; ht += cnt; }
    if (f) tok[offs + wp] = yt;
    total += ht;
    __syncthreads();
  }
  const int L = total;

  // ---- Phase B: A[tk][r] = bf16(-log(clip(p))), B_u16[x] = A_u16[x+1] ----
  for (int r = t; r < NLEN; r += 256) {
    const float4* rp = (const float4*)(y_pred + ((size_t)b * NLEN + r) * NTOK);
    float4 q[8]; float s = 0.f;
#pragma unroll
    for (int u = 0; u < 8; ++u) { q[u] = rp[u]; s += q[u].x + q[u].y + q[u].z + q[u].w; }
    float inv = 1.0f / s;
#pragma unroll
    for (int u = 0; u < 8; ++u) {
      float pv[4] = {q[u].x, q[u].y, q[u].z, q[u].w};
#pragma unroll
      for (int c2 = 0; c2 < 4; ++c2) {
        float p = pv[c2] * inv;
        p = fminf(fmaxf(p, EPS_F), 1.0f - EPS_F);
        ushort v = f2bf(-__logf(p));
        int tk = u * 4 + c2;
        nlA[tk * 1024 + r] = v;
        if (r > 0) nlB[tk * 1024 + r - 1] = v;
      }
    }
  }
  __syncthreads();

  // ---- Row-0 prefix: P0s[m] = D[0][m+1] = sum_{r<=m} ins[r] ----
  {
    const ushort4 iv4 = *(const ushort4*)(nlA + PADT * 1024 + 4 * t);
    float i0v = __uint_as_float(((unsigned)iv4.x) << 16);
    float i1v = __uint_as_float(((unsigned)iv4.y) << 16);
    float i2v = __uint_as_float(((unsigned)iv4.z) << 16);
    float i3v = __uint_as_float(((unsigned)iv4.w) << 16);
    float p1 = i0v, p2 = i0v + i1v, p3 = p2 + i2v, s4 = p3 + i3v;
    float x = s4;
#pragma unroll
    for (int d = 1; d < 64; d <<= 1) {
      float y = __shfl_up(x, d);
      if (lane >= d) x += y;
    }
    if (lane == 63) wtmp[wv] = x;
    __syncthreads();
    float pre = x - s4;
#pragma unroll
    for (int w2 = 0; w2 < NWAVE; ++w2) if (w2 < wv) pre += wtmp[w2];
    *(float4*)(P0s + 4 * t) = make_float4(pre + p1, pre + p2, pre + p3, pre + s4);
  }

  // ---- DP state: lane owns rows r0 = 2t+1, r1 = 2t+2 ----
  const int r0 = 2 * t + 1;
  const int tk0 = tok[2 * t];
  const int tk1 = tok[2 * t + 1];
  float dcur0 = (float)r0;        // D[r0][0]
  float dcur1 = (float)(r0 + 1);  // D[r1][0]
  float diag0 = (float)(r0 - 1);  // D[r0-1][0]
  float wq0 = 0, wq1 = 0, wq2 = 0, wq3 = 0;

  const unsigned* baseA = (const unsigned*)nlA;   // pair j = (A[2j], A[2j+1])
  const unsigned* baseB = (const unsigned*)nlB;   // pair j = (A[2j+1], A[2j+2])

  // ---- systolic chunk phases ----
  for (int p = 0; p < NPHASE; ++p) {
    __syncthreads();
    const int c = p - wv;
    if (c < 0 || c >= NC) continue;
    const int base = c * CCH;
    const int i0 = base - lane;          // absolute stream element at slot 0
    const int par = i0 & 1;
    const int joff = (i0 - par) >> 1;    // pair index (i0-par is even)
    const unsigned* tb = par ? baseB : baseA;
    unsigned a0 = lds_off(tb + tk0 * 512 + joff);
    unsigned a1 = lds_off(tb + tk1 * 512 + joff);
    unsigned ai = lds_off(tb + PADT * 512 + joff);
    unsigned ab = (wv == 0) ? lds_off(P0s + base)
                            : lds_off(bnd + ((wv - 1) * 2 + (p & 1)) * RSTR);
    float* bw = (wv < 3) ? (bnd + (wv * 2 + ((p + 1) & 1)) * RSTR)
                         : (bnd + 6 * RSTR);   // wave 3 -> dead buffer

    unsigned u0a[4], u1a[4], uia[4]; f32x4 ba4[2];
    unsigned u0b[4], u1b[4], uib[4]; f32x4 bb4[2];

    // prime: loads for iter 0 into group A (14 outstanding)
    ISSUE_LOADS(u0a, u1a, uia, ba4)

    int sb = 0;
    for (int it = 0; it < 4; ++it) { STEP_AB(true)  STEP_BA(true)  }   // sb 0..63
    for (int it = 0; it < 4; ++it) { STEP_AB(false) STEP_BA(false) }   // sb 64..127
    for (int it = 0; it < 4; ++it) { STEP_AB(true)  STEP_BA(true)  }   // sb 128..191
  }

  // ---- extract D[L][1024] ----
  if (r0 == L) partial[b] = dcur0;
  if (r0 + 1 == L) partial[b] = dcur1;
  if (L == 0 && t == 0) partial[b] = P0s[NLEN - 1];
}

__global__ void reduce_kernel(const float* __restrict__ partial, float* __restrict__ out) {
  if (threadIdx.x == 0) {
    float s = 0.f;
    for (int b2 = 0; b2 < 32; ++b2) s += partial[b2];
    out[0] = s;
  }
}

extern "C" void kernel_launch(void* const* d_in, const int* in_sizes, int n_in,
                              void* d_out, int out_size, void* d_ws, size_t ws_size,
                              hipStream_t stream) {
  const int*   y_true = (const int*)d_in[0];
  const float* y_pred = (const float*)d_in[1];
  float* out = (float*)d_out;
  float* partial = (float*)d_ws;

  const size_t lds_bytes = (size_t)LDS_FLOATS * sizeof(float);   // 145,216 B
  hipFuncSetAttribute((const void*)align_loss_kernel,
                      hipFuncAttributeMaxDynamicSharedMemorySize, (int)lds_bytes);

  hipLaunchKernelGGL(align_loss_kernel, dim3(32), dim3(256), lds_bytes, stream,
                     y_true, y_pred, partial);
  hipLaunchKernelGGL(reduce_kernel, dim3(1), dim3(64), 0, stream, partial, out);
}